// Round 1
// baseline (396.821 us; speedup 1.0000x reference)
//
#include <hip/hip_runtime.h>
#include <hip/hip_bf16.h>
#include <math.h>

// MultiBoxLoss (RetinaFace-style): B=64, P=16800, G=32, C=2.
// Pipeline: init -> best-prior-per-gt -> match+per-element losses -> per-batch
// exact top-k (radix select) for hard negative mining -> final scalars.

__device__ __forceinline__ float sl1(float x) {
    float ax = fabsf(x);
    return ax < 1.f ? 0.5f * ax * ax : ax - 0.5f;
}

// block-wide sum, blockDim.x == 256 (4 waves). Result valid on all threads.
__device__ __forceinline__ float block_sum(float v, float* buf) {
    #pragma unroll
    for (int o = 32; o > 0; o >>= 1) v += __shfl_down(v, o, 64);
    int lane = threadIdx.x & 63, w = threadIdx.x >> 6;
    __syncthreads();               // protect buf reuse across calls
    if (lane == 0) buf[w] = v;
    __syncthreads();
    return buf[0] + buf[1] + buf[2] + buf[3];
}

__global__ void k_init(int* __restrict__ ibase, int n) {
    int i = blockIdx.x * blockDim.x + threadIdx.x;
    if (i < n) ibase[i] = 0;
}

// ---- Kernel A: per (b,g) best prior (argmax over P, first-index ties) ----
__global__ __launch_bounds__(256)
void k_bestprior(const float4* __restrict__ priors, const float* __restrict__ targets,
                 int* __restrict__ bpi, int* __restrict__ vgt, int* __restrict__ anyv,
                 int G, int P) {
    const int GPB = 8;
    int b = blockIdx.y;
    int g0 = blockIdx.x * GPB;
    int ng = min(GPB, G - g0);
    int tid = threadIdx.x;
    __shared__ float4 s_box[GPB];
    if (tid < ng) {
        const float* t = targets + ((size_t)b * G + g0 + tid) * 15;
        s_box[tid] = make_float4(t[0], t[1], t[2], t[3]);
    }
    __syncthreads();
    float bv[GPB]; int bi[GPB];
    #pragma unroll
    for (int j = 0; j < GPB; j++) { bv[j] = -1.f; bi[j] = 0; }
    for (int p = tid; p < P; p += 256) {
        float4 pr = priors[p];
        float px0 = pr.x - pr.z * 0.5f, py0 = pr.y - pr.w * 0.5f;
        float px1 = pr.x + pr.z * 0.5f, py1 = pr.y + pr.w * 0.5f;
        float area_p = (px1 - px0) * (py1 - py0);
        #pragma unroll
        for (int j = 0; j < GPB; j++) {
            if (j < ng) {
                float4 tb = s_box[j];
                float lx = fmaxf(tb.x, px0), ly = fmaxf(tb.y, py0);
                float rx = fminf(tb.z, px1), ry = fminf(tb.w, py1);
                float w = fmaxf(rx - lx, 0.f), h = fmaxf(ry - ly, 0.f);
                float inter = w * h;
                float at = (tb.z - tb.x) * (tb.w - tb.y);
                float iou = inter / (at + area_p - inter);
                if (iou > bv[j]) { bv[j] = iou; bi[j] = p; }
            }
        }
    }
    __shared__ float sv[256];
    __shared__ int si[256];
    for (int j = 0; j < ng; j++) {
        float mv; int mi;
        switch (j) {  // compile-time indexed access
            case 0: mv = bv[0]; mi = bi[0]; break;
            case 1: mv = bv[1]; mi = bi[1]; break;
            case 2: mv = bv[2]; mi = bi[2]; break;
            case 3: mv = bv[3]; mi = bi[3]; break;
            case 4: mv = bv[4]; mi = bi[4]; break;
            case 5: mv = bv[5]; mi = bi[5]; break;
            case 6: mv = bv[6]; mi = bi[6]; break;
            default: mv = bv[7]; mi = bi[7]; break;
        }
        sv[tid] = mv; si[tid] = mi;
        __syncthreads();
        for (int s = 128; s > 0; s >>= 1) {
            if (tid < s) {
                float v2 = sv[tid + s]; int i2 = si[tid + s];
                if (v2 > sv[tid] || (v2 == sv[tid] && i2 < si[tid])) { sv[tid] = v2; si[tid] = i2; }
            }
            __syncthreads();
        }
        if (tid == 0) {
            int g = g0 + j;
            bpi[b * G + g] = si[0];
            int valid = sv[0] >= 0.2f ? 1 : 0;
            vgt[b * G + g] = valid;
            if (valid) atomicOr(&anyv[b], 1);
        }
        __syncthreads();
    }
}

// ---- Kernel B: per-prior match + per-element losses ----
__global__ __launch_bounds__(256)
void k_match(const float2* __restrict__ cls, const float4* __restrict__ loc,
             const float* __restrict__ lmd, const float4* __restrict__ priors,
             const float* __restrict__ targets, const int* __restrict__ bpi,
             const int* __restrict__ vgt, const int* __restrict__ anyv,
             float* __restrict__ bc, int* __restrict__ npos,
             int* __restrict__ icnt, float* __restrict__ facc,
             int G, int P) {
    int b = blockIdx.y;
    int p = blockIdx.x * 256 + threadIdx.x;
    int tid = threadIdx.x;
    __shared__ float s_t[64 * 4];
    __shared__ float s_lm[64 * 10];
    __shared__ float s_lab[64];
    __shared__ int s_bpi[64];
    __shared__ int s_v[64];
    for (int i = tid; i < G * 15; i += 256) {
        int g = i / 15, j = i - g * 15;
        float v = targets[((size_t)b * G + g) * 15 + j];
        if (j < 4) s_t[g * 4 + j] = v;
        else if (j < 14) s_lm[g * 10 + (j - 4)] = v;
        else s_lab[g] = v;
    }
    for (int i = tid; i < G; i += 256) { s_bpi[i] = bpi[b * G + i]; s_v[i] = vgt[b * G + i]; }
    __syncthreads();
    int av = anyv[b];

    float v_ll = 0.f, v_lmm = 0.f, v_lcp = 0.f, v_np = 0.f, v_np1 = 0.f;
    if (p < P) {
        float4 pr = priors[p];
        float px0 = pr.x - pr.z * 0.5f, py0 = pr.y - pr.w * 0.5f;
        float px1 = pr.x + pr.z * 0.5f, py1 = pr.y + pr.w * 0.5f;
        float area_p = (px1 - px0) * (py1 - py0);
        float btv = -1.f; int bti = 0;
        int fidx = -1, fvalid = 0;
        for (int g = 0; g < G; g++) {
            float tx0 = s_t[g * 4], ty0 = s_t[g * 4 + 1], tx1 = s_t[g * 4 + 2], ty1 = s_t[g * 4 + 3];
            float lx = fmaxf(tx0, px0), ly = fmaxf(ty0, py0);
            float rx = fminf(tx1, px1), ry = fminf(ty1, py1);
            float w = fmaxf(rx - lx, 0.f), h = fmaxf(ry - ly, 0.f);
            float inter = w * h;
            float at = (tx1 - tx0) * (ty1 - ty0);
            float iou = inter / (at + area_p - inter);
            if (iou > btv) { btv = iou; bti = g; }           // first-max over g
            if (s_bpi[g] == p) { fidx = g; if (s_v[g]) fvalid = 1; }  // scatter-max over g
        }
        // forced_ov is 2.0 only for valid gts; btv in [0,1] so max==2 iff fvalid
        float btv2 = fvalid ? 2.f : btv;
        int bti2 = (fidx >= 0) ? fidx : bti;   // forced_idx uses ALL gts (incl. invalid)
        int conf = 0;
        if (av && btv2 >= 0.35f) conf = (int)s_lab[bti2];
        bool pos = conf != 0;

        float2 c = cls[(size_t)b * P + p];
        float m = fmaxf(c.x, c.y);
        float logz = m + logf(expf(c.x - m) + expf(c.y - m));
        float gold = pos ? c.y : c.x;          // conf_t -> {0,1}
        float lc = logz - gold;                // >= 0
        bc[(size_t)b * P + p] = pos ? 0.f : lc;

        if (pos) {
            v_np = 1.f; v_lcp = lc;
            float tx0 = s_t[bti2 * 4], ty0 = s_t[bti2 * 4 + 1];
            float tx1 = s_t[bti2 * 4 + 2], ty1 = s_t[bti2 * 4 + 3];
            float dw = 0.1f * pr.z, dh = 0.1f * pr.w;
            float lt0 = ((tx0 + tx1) * 0.5f - pr.x) / dw;
            float lt1 = ((ty0 + ty1) * 0.5f - pr.y) / dh;
            float lt2 = logf((tx1 - tx0) / pr.z) / 0.2f;
            float lt3 = logf((ty1 - ty0) / pr.w) / 0.2f;
            float4 ld = loc[(size_t)b * P + p];
            v_ll = sl1(ld.x - lt0) + sl1(ld.y - lt1) + sl1(ld.z - lt2) + sl1(ld.w - lt3);
            if (conf > 0) {
                v_np1 = 1.f;
                const float* lp = lmd + ((size_t)b * P + p) * 10;
                float s = 0.f;
                #pragma unroll
                for (int q = 0; q < 5; q++) {
                    float gx = (s_lm[bti2 * 10 + 2 * q]     - pr.x) / dw;
                    float gy = (s_lm[bti2 * 10 + 2 * q + 1] - pr.y) / dh;
                    s += sl1(lp[2 * q] - gx) + sl1(lp[2 * q + 1] - gy);
                }
                v_lmm = s;
            }
        }
    }
    __shared__ float rbuf[4];
    float bs;
    bs = block_sum(v_ll, rbuf);
    if (tid == 0 && bs != 0.f) atomicAdd(&facc[0], bs);
    bs = block_sum(v_lmm, rbuf);
    if (tid == 0 && bs != 0.f) atomicAdd(&facc[1], bs);
    bs = block_sum(v_lcp, rbuf);
    if (tid == 0 && bs != 0.f) atomicAdd(&facc[2], bs);
    bs = block_sum(v_np, rbuf);
    if (tid == 0) { int n = (int)(bs + 0.5f); if (n) { atomicAdd(&npos[b], n); atomicAdd(&icnt[0], n); } }
    bs = block_sum(v_np1, rbuf);
    if (tid == 0) { int n = (int)(bs + 0.5f); if (n) atomicAdd(&icnt[1], n); }
}

// ---- Kernel C: per-batch exact top-k sum via 4x8-bit radix select ----
__global__ __launch_bounds__(256)
void k_select(const float* __restrict__ bc, const int* __restrict__ npos,
              float* __restrict__ facc, int P) {
    int b = blockIdx.x;
    int tid = threadIdx.x;
    const float* v = bc + (size_t)b * P;
    long long k = (long long)7 * npos[b];
    if (k > P - 1) k = P - 1;
    if (k <= 0) return;

    __shared__ unsigned hist[256];
    __shared__ int suf[257];
    __shared__ unsigned s_pref;
    __shared__ int s_rem;
    unsigned prefix = 0;
    int rem = (int)k;
    for (int shift = 24; shift >= 0; shift -= 8) {
        hist[tid] = 0;
        __syncthreads();
        unsigned himask = (shift == 24) ? 0u : (0xFFFFFFFFu << (shift + 8));
        for (int i = tid; i < P; i += 256) {
            unsigned u = __float_as_uint(v[i]);   // all values >= 0 -> bits are order-preserving
            if ((u & himask) == prefix) atomicAdd(&hist[(u >> shift) & 255u], 1u);
        }
        __syncthreads();
        suf[tid] = (int)hist[tid];
        if (tid == 0) suf[256] = 0;
        __syncthreads();
        #pragma unroll
        for (int o = 1; o < 256; o <<= 1) {   // inclusive suffix sum (Hillis-Steele)
            int t = (tid + o < 256) ? suf[tid + o] : 0;
            __syncthreads();
            suf[tid] += t;
            __syncthreads();
        }
        int above = suf[tid + 1];
        if (above < rem && rem <= suf[tid]) {  // exactly one thread matches
            s_pref = prefix | ((unsigned)tid << shift);
            s_rem = rem - above;
        }
        __syncthreads();
        prefix = s_pref; rem = s_rem;
        __syncthreads();
    }
    float T = __uint_as_float(prefix);  // k-th largest value
    float sum = 0.f; float cnt = 0.f;
    for (int i = tid; i < P; i += 256) {
        float x = v[i];
        if (x > T) { sum += x; cnt += 1.f; }
    }
    __shared__ float fb[4];
    float ts = block_sum(sum, fb);
    float tc = block_sum(cnt, fb);
    if (tid == 0) {
        long long cg = (long long)(tc + 0.5f);
        atomicAdd(&facc[3], ts + (float)(k - cg) * T);
    }
}

__global__ void k_final(const float* __restrict__ facc, const int* __restrict__ icnt,
                        float* __restrict__ out) {
    if (threadIdx.x == 0) {
        float N = fmaxf((float)icnt[0], 1.f);
        float N1 = fmaxf((float)icnt[1], 1.f);
        out[0] = facc[0] / N;
        out[1] = (facc[2] + facc[3]) / N;
        out[2] = facc[1] / N1;
    }
}

extern "C" void kernel_launch(void* const* d_in, const int* in_sizes, int n_in,
                              void* d_out, int out_size, void* d_ws, size_t ws_size,
                              hipStream_t stream) {
    const float* cls     = (const float*)d_in[0];
    const float* loc     = (const float*)d_in[1];
    const float* lmd     = (const float*)d_in[2];
    const float* priors  = (const float*)d_in[3];
    const float* targets = (const float*)d_in[4];
    int P  = in_sizes[3] / 4;
    int BP = in_sizes[1] / 4;
    int B  = BP / P;
    int G  = in_sizes[4] / (15 * B);

    // workspace layout
    float* bc  = (float*)d_ws;                      // B*P
    int* ibase = (int*)(bc + (size_t)B * P);
    int* bpi   = ibase;                             // B*G
    int* vgt   = bpi + B * G;                       // B*G
    int* anyv  = vgt + B * G;                       // B
    int* npos  = anyv + B;                          // B
    int* icnt  = npos + B;                          // 2: npos_total, npos1_total
    float* facc = (float*)(icnt + 2);               // 4: loss_l, loss_landm, lc_pos, topk
    int n_ints = 2 * B * G + 2 * B + 2 + 4;

    k_init<<<(n_ints + 255) / 256, 256, 0, stream>>>(ibase, n_ints);
    dim3 gA((G + 7) / 8, B);
    k_bestprior<<<gA, 256, 0, stream>>>((const float4*)priors, targets, bpi, vgt, anyv, G, P);
    dim3 gB((P + 255) / 256, B);
    k_match<<<gB, 256, 0, stream>>>((const float2*)cls, (const float4*)loc, lmd,
                                    (const float4*)priors, targets, bpi, vgt, anyv,
                                    bc, npos, icnt, facc, G, P);
    k_select<<<B, 256, 0, stream>>>(bc, npos, facc, P);
    k_final<<<1, 64, 0, stream>>>(facc, icnt, (float*)d_out);
}